// Round 7
// baseline (824.659 us; speedup 1.0000x reference)
//
#include <hip/hip_runtime.h>
#include <stdint.h>

#define B_ 128
#define N_ 4096
#define M_ 64
#define D_ 16
#define NSLICE 32                  // n-slices of 128 n each
#define SLICE_N 128
#define WAVE_N 32                  // n handled per wave
#define OUT_ELEMS (B_ * M_ * D_)   // 131072
#define OUT4 (OUT_ELEMS / 4)       // 32768 float4 columns
#define PART_BYTES ((size_t)NSLICE * OUT_ELEMS * sizeof(float))  // 16.8 MB

#if __has_builtin(__builtin_amdgcn_exp2f)
#define EXP2F(x) __builtin_amdgcn_exp2f(x)
#else
#define EXP2F(x) __expf((x) * 0.69314718f)
#endif

// ---------- DPP wave64 sum (VALU pipe; canonical masked bcast cascade) -----
template<int CTRL, int RM, int BC>
__device__ __forceinline__ float dpp_f(float old, float src) {
  return __int_as_float(__builtin_amdgcn_update_dpp(
      __float_as_int(old), __float_as_int(src), CTRL, RM, 0xF, BC));
}

__device__ __forceinline__ float wave_sum64(float x) {
  x += dpp_f<0x121, 0xF, 1>(0.f, x);   // row_ror:1
  x += dpp_f<0x122, 0xF, 1>(0.f, x);   // row_ror:2
  x += dpp_f<0x124, 0xF, 1>(0.f, x);   // row_ror:4
  x += dpp_f<0x128, 0xF, 1>(0.f, x);   // row_ror:8 -> lane holds 16-lane row sum
  x += dpp_f<0x142, 0xA, 1>(0.f, x);   // bcast15, rows 1,3 only
  x += dpp_f<0x143, 0xC, 1>(0.f, x);   // bcast31, rows 2,3 only; lane63 = total
  return __int_as_float(__builtin_amdgcn_readlane(__float_as_int(x), 63));
}

// ---------------------------------------------------------------------------
// lane m <-> capsule m. Per (b,n): vote[16] = X(4x4) @ W_n,m(4x4),
// qk = <vote, ncv'[b,m]> (ncv' pre-scaled by 0.25*log2e), p = exp2(qk),
// softmax across 64 lanes via DPP sum + rcp, acc[m][:] += r*vote.
// Block = 2 b's x 128 n; 4 waves SPLIT N (32 n each, same 2 b's); wave accs
// combined by an intra-block LDS tree (reuses x-LDS). Grid 2048 = 64 bg x
// 32 slices. Partials: 32 x 0.5 MB = 16.8 MB (4x less than before).
// Swizzle: XCD k (=inner&7) owns slices {4k..4k+3} -> rolling 2 MB w-window
// per XCD L2. NO fences/atomics in this path (round-5 lesson: per-block
// device-scope fences = buffer_wbl2 storms, 4x regression).
// EPI=1: partials to ws. EPI=0: atomicAdd fallback.
// ---------------------------------------------------------------------------
template<int EPI>
__global__ __launch_bounds__(256, 8)
void capsule_main(const float* __restrict__ x_in, const float* __restrict__ ncv_in,
                  const float* __restrict__ w_in, float* __restrict__ dst) {
  const int L     = blockIdx.x;                       // 0..2047
  const int bg    = L >> 5;                           // 0..63
  const int inner = L & 31;
  const int s     = ((inner & 7) << 2) | (inner >> 3);// 0..31, XCD = inner&7
  const int lane  = threadIdx.x & 63;                 // = m
  const int wid   = __builtin_amdgcn_readfirstlane((int)(threadIdx.x >> 6));
  const int t     = threadIdx.x;
  const int b0    = bg * 2;
  const int n0    = s * SLICE_N;

  __shared__ float xls[2 * SLICE_N * D_];             // 16KB: [b<2][n<128][f<16]

  // ---- stage x once (coalesced float4; 4 per thread) ----
#pragma unroll
  for (int k = 0; k < 4; ++k) {
    const int g   = t + 256 * k;                      // float4 idx, 0..1023
    const int b8  = g >> 9;                           // 0..1
    const int rem = g & 511;                          // n*4 + q
    ((float4*)xls)[g] =
        ((const float4*)x_in)[((size_t)(b0 + b8) * N_ + n0) * 4 + rem];
  }

  // persistent per-lane ncv[b][m][0..15], pre-scaled by 0.25*log2(e):
  // p = exp2(qk') == exp(qk*0.25). ncv feeds ONLY the qk dot.
  const float QS = 0.25f * 1.44269504f;
  float ncv[2][16];
#pragma unroll
  for (int bb = 0; bb < 2; ++bb) {
    const float4* p = (const float4*)(ncv_in + ((size_t)(b0 + bb) * M_ + lane) * D_);
#pragma unroll
    for (int q = 0; q < 4; ++q) {
      float4 v = p[q];
      ncv[bb][q*4+0] = v.x * QS; ncv[bb][q*4+1] = v.y * QS;
      ncv[bb][q*4+2] = v.z * QS; ncv[bb][q*4+3] = v.w * QS;
    }
  }

  float acc[2][16];
#pragma unroll
  for (int bb = 0; bb < 2; ++bb)
#pragma unroll
    for (int j = 0; j < 16; ++j) acc[bb][j] = 0.f;

  __syncthreads();                                    // x visible

  // this wave's 32-n window
  const float* wpb = w_in + (size_t)(n0 + wid * WAVE_N) * 1024 + lane;

#pragma unroll 2
  for (int i = 0; i < WAVE_N; ++i) {
    // w column for lane m (L2-resident; 16 coalesced 256B-stride loads)
    float wv[16];
#pragma unroll
    for (int xd = 0; xd < 16; ++xd) wv[xd] = wpb[(size_t)i * 1024 + xd * 64];

#pragma unroll
    for (int bb = 0; bb < 2; ++bb) {
      const float4* xp4 =
          (const float4*)&xls[(bb * SLICE_N + wid * WAVE_N + i) * D_];
      float xv[16];
#pragma unroll
      for (int q = 0; q < 4; ++q) {
        float4 v = xp4[q];
        xv[q*4+0] = v.x; xv[q*4+1] = v.y; xv[q*4+2] = v.z; xv[q*4+3] = v.w;
      }
      // vote[a*4+d] = sum_x xv[a*4+x] * wv[x*4+d]
      float vote[16];
#pragma unroll
      for (int a = 0; a < 4; ++a) {
#pragma unroll
        for (int d = 0; d < 4; ++d) {
          float v = xv[a*4+0] * wv[0*4+d];
          v = fmaf(xv[a*4+1], wv[1*4+d], v);
          v = fmaf(xv[a*4+2], wv[2*4+d], v);
          v = fmaf(xv[a*4+3], wv[3*4+d], v);
          vote[a*4+d] = v;
        }
      }
      // scores ~N(0,0.125^2): max-subtraction unnecessary (shift-invariant)
      float q0 = 0.f, q1 = 0.f, q2 = 0.f, q3 = 0.f;
#pragma unroll
      for (int j = 0; j < 4; ++j) {
        q0 = fmaf(vote[j],      ncv[bb][j],      q0);
        q1 = fmaf(vote[4 + j],  ncv[bb][4 + j],  q1);
        q2 = fmaf(vote[8 + j],  ncv[bb][8 + j],  q2);
        q3 = fmaf(vote[12 + j], ncv[bb][12 + j], q3);
      }
      const float sc = (q0 + q1) + (q2 + q3);
      const float p  = EXP2F(sc);
      const float sm = wave_sum64(p);
      const float rr = p * __builtin_amdgcn_rcpf(sm);
#pragma unroll
      for (int j = 0; j < 16; ++j) acc[bb][j] = fmaf(rr, vote[j], acc[bb][j]);
    }
  }

  if (EPI == 0) {
#pragma unroll
    for (int bb = 0; bb < 2; ++bb) {
      float* op = dst + ((size_t)(b0 + bb) * M_ + lane) * D_;
#pragma unroll
      for (int j = 0; j < 16; ++j) atomicAdd(op + j, acc[bb][j]);
    }
    return;
  }

  // ---- intra-block 4-wave reduce (reuse xls), write slice-s partials ----
  // value layout per round: xls[w<4][lane<64][j<16]; thread t then owns
  // row m = t>>2, elems j = (t&3)*4..+3  ->  float4 col (b*256 + t).
  float4* x4 = (float4*)xls;
#pragma unroll
  for (int bb = 0; bb < 2; ++bb) {
    __syncthreads();                  // bb=0: x reads done; bb=1: prev reads done
#pragma unroll
    for (int q = 0; q < 4; ++q) {
      float4 v;
      v.x = acc[bb][q*4+0]; v.y = acc[bb][q*4+1];
      v.z = acc[bb][q*4+2]; v.w = acc[bb][q*4+3];
      x4[wid * 256 + lane * 4 + q] = v;
    }
    __syncthreads();
    const float4 s0 = x4[t], s1 = x4[256 + t], s2 = x4[512 + t], s3 = x4[768 + t];
    float4 r;
    r.x = (s0.x + s1.x) + (s2.x + s3.x);
    r.y = (s0.y + s1.y) + (s2.y + s3.y);
    r.z = (s0.z + s1.z) + (s2.z + s3.z);
    r.w = (s0.w + s1.w) + (s2.w + s3.w);
    ((float4*)dst)[((size_t)s * B_ + b0 + bb) * 256 + t] = r;
  }
}

// ---------- single tail: sum 32 slices + fused LayerNorm over D=16 ---------
__global__ void reduce_ln(const float4* __restrict__ ws4, float4* __restrict__ out4,
                          const float* __restrict__ lw, const float* __restrict__ lb) {
  const int f = blockIdx.x * 256 + threadIdx.x;       // 0..32767 = (b*64+m)*4+q
  float4 s = {0.f, 0.f, 0.f, 0.f};
#pragma unroll 8
  for (int sl = 0; sl < NSLICE; ++sl) {
    const float4 a = ws4[(size_t)sl * OUT4 + f];
    s.x += a.x; s.y += a.y; s.z += a.z; s.w += a.w;
  }
  // LN over 16 elems: 4 consecutive lanes (q=f&3) share one (b,m) row
  float sv = (s.x + s.y) + (s.z + s.w);
  sv += __shfl_xor(sv, 1, 4);
  sv += __shfl_xor(sv, 2, 4);
  const float mu = sv * 0.0625f;
  float4 d;
  d.x = s.x - mu; d.y = s.y - mu; d.z = s.z - mu; d.w = s.w - mu;
  float s2 = (d.x*d.x + d.y*d.y) + (d.z*d.z + d.w*d.w);
  s2 += __shfl_xor(s2, 1, 4);
  s2 += __shfl_xor(s2, 2, 4);
  const float inv = rsqrtf(s2 * 0.0625f + 1e-5f);
  const float4 w4 = ((const float4*)lw)[f & 3];
  const float4 b4 = ((const float4*)lb)[f & 3];
  float4 o;
  o.x = d.x * inv * w4.x + b4.x; o.y = d.y * inv * w4.y + b4.y;
  o.z = d.z * inv * w4.z + b4.z; o.w = d.w * inv * w4.w + b4.w;
  out4[f] = o;
}

// ---------- fallback LN (atomic path), in place on d_out -------------------
__global__ void capsule_ln(float* __restrict__ out, const float* __restrict__ lw,
                           const float* __restrict__ lb) {
  const int t = blockIdx.x * 256 + threadIdx.x;
  const float v = out[t];
  float sv = v;
#pragma unroll
  for (int m = 1; m < 16; m <<= 1) sv += __shfl_xor(sv, m, 16);
  const float mu = sv * 0.0625f;
  const float dv = v - mu;
  float s2 = dv * dv;
#pragma unroll
  for (int m = 1; m < 16; m <<= 1) s2 += __shfl_xor(s2, m, 16);
  out[t] = dv * rsqrtf(s2 * 0.0625f + 1e-5f) * lw[t & 15] + lb[t & 15];
}

extern "C" void kernel_launch(void* const* d_in, const int* in_sizes, int n_in,
                              void* d_out, int out_size, void* d_ws, size_t ws_size,
                              hipStream_t stream) {
  (void)in_sizes; (void)n_in; (void)out_size;
  const float* x_in = (const float*)d_in[0];
  const float* ncv  = (const float*)d_in[1];
  const float* w    = (const float*)d_in[2];
  const float* lw   = (const float*)d_in[3];
  const float* lb   = (const float*)d_in[4];
  // d_in[5] = num_iter (==1): routing body runs once, matching reference
  float* out = (float*)d_out;

  if (ws_size >= PART_BYTES) {
    float* ws = (float*)d_ws;
    capsule_main<1><<<2048, 256, 0, stream>>>(x_in, ncv, w, ws);
    reduce_ln<<<OUT4 / 256, 256, 0, stream>>>((const float4*)ws, (float4*)out, lw, lb);
  } else {
    hipMemsetAsync(out, 0, sizeof(float) * OUT_ELEMS, stream);
    capsule_main<0><<<2048, 256, 0, stream>>>(x_in, ncv, w, out);
    capsule_ln<<<OUT_ELEMS / 256, 256, 0, stream>>>(out, lw, lb);
  }
}

// Round 8
// 186.725 us; speedup vs baseline: 4.4164x; 4.4164x over previous
//
#include <hip/hip_runtime.h>
#include <stdint.h>

#define B_ 128
#define N_ 4096
#define M_ 64
#define D_ 16
#define NSLICE 32                  // n-slices of 128 n each
#define SLICE_N 128
#define WAVE_N 32                  // n handled per wave
#define OUT_ELEMS (B_ * M_ * D_)   // 131072
#define OUT4 (OUT_ELEMS / 4)       // 32768 float4 columns
#define PART_BYTES ((size_t)NSLICE * OUT_ELEMS * sizeof(float))  // 16.8 MB

#if __has_builtin(__builtin_amdgcn_exp2f)
#define EXP2F(x) __builtin_amdgcn_exp2f(x)
#else
#define EXP2F(x) __expf((x) * 0.69314718f)
#endif

// ---------- DPP wave64 sum (VALU pipe; canonical masked bcast cascade) -----
template<int CTRL, int RM, int BC>
__device__ __forceinline__ float dpp_f(float old, float src) {
  return __int_as_float(__builtin_amdgcn_update_dpp(
      __float_as_int(old), __float_as_int(src), CTRL, RM, 0xF, BC));
}

__device__ __forceinline__ float wave_sum64(float x) {
  x += dpp_f<0x121, 0xF, 1>(0.f, x);   // row_ror:1
  x += dpp_f<0x122, 0xF, 1>(0.f, x);   // row_ror:2
  x += dpp_f<0x124, 0xF, 1>(0.f, x);   // row_ror:4
  x += dpp_f<0x128, 0xF, 1>(0.f, x);   // row_ror:8 -> lane holds 16-lane row sum
  x += dpp_f<0x142, 0xA, 1>(0.f, x);   // bcast15, rows 1,3 only
  x += dpp_f<0x143, 0xC, 1>(0.f, x);   // bcast31, rows 2,3 only; lane63 = total
  return __int_as_float(__builtin_amdgcn_readlane(__float_as_int(x), 63));
}

// ---------------------------------------------------------------------------
// lane m <-> capsule m. Per (b,n): vote[16] = X(4x4) @ W_n,m(4x4),
// qk = <vote, ncv'[b,m]> (ncv' pre-scaled by 0.25*log2e), p = exp2(qk),
// softmax across 64 lanes via DPP sum + rcp, acc[m][:] += r*vote.
// Block = 2 b's x 128 n; 4 waves split N (32 n each); wave accs combined by
// an intra-block LDS tree (reuses x-LDS). Grid 2048 = 64 bg x 32 slices.
// Partials: 32 x 0.5 MB = 16.8 MB. Swizzle: XCD k (=inner&7) owns slices
// {4k..4k+3} -> rolling 2 MB w-window per XCD L2.
// LESSONS BAKED IN: (r5) no per-block device-scope fences (buffer_wbl2
// storms); (r7) launch_bounds(256,8) forces VGPR=32 -> spill catastrophe,
// 3.4 GB scratch traffic. (256,4) gives VGPR~60 and HW can still reach
// 8 waves/SIMD since 60 <= 64.
// EPI=1: partials to ws. EPI=0: atomicAdd fallback.
// ---------------------------------------------------------------------------
template<int EPI>
__global__ __launch_bounds__(256, 4)
void capsule_main(const float* __restrict__ x_in, const float* __restrict__ ncv_in,
                  const float* __restrict__ w_in, float* __restrict__ dst) {
  const int L     = blockIdx.x;                       // 0..2047
  const int bg    = L >> 5;                           // 0..63
  const int inner = L & 31;
  const int s     = ((inner & 7) << 2) | (inner >> 3);// 0..31, XCD = inner&7
  const int lane  = threadIdx.x & 63;                 // = m
  const int wid   = __builtin_amdgcn_readfirstlane((int)(threadIdx.x >> 6));
  const int t     = threadIdx.x;
  const int b0    = bg * 2;
  const int n0    = s * SLICE_N;

  __shared__ float xls[2 * SLICE_N * D_];             // 16KB: [b<2][n<128][f<16]

  // ---- stage x once (coalesced float4; 4 per thread) ----
#pragma unroll
  for (int k = 0; k < 4; ++k) {
    const int g   = t + 256 * k;                      // float4 idx, 0..1023
    const int b8  = g >> 9;                           // 0..1
    const int rem = g & 511;                          // n*4 + q
    ((float4*)xls)[g] =
        ((const float4*)x_in)[((size_t)(b0 + b8) * N_ + n0) * 4 + rem];
  }

  // persistent per-lane ncv[b][m][0..15], pre-scaled by 0.25*log2(e):
  // p = exp2(qk') == exp(qk*0.25). ncv feeds ONLY the qk dot.
  const float QS = 0.25f * 1.44269504f;
  float ncv[2][16];
#pragma unroll
  for (int bb = 0; bb < 2; ++bb) {
    const float4* p = (const float4*)(ncv_in + ((size_t)(b0 + bb) * M_ + lane) * D_);
#pragma unroll
    for (int q = 0; q < 4; ++q) {
      float4 v = p[q];
      ncv[bb][q*4+0] = v.x * QS; ncv[bb][q*4+1] = v.y * QS;
      ncv[bb][q*4+2] = v.z * QS; ncv[bb][q*4+3] = v.w * QS;
    }
  }

  float acc[2][16];
#pragma unroll
  for (int bb = 0; bb < 2; ++bb)
#pragma unroll
    for (int j = 0; j < 16; ++j) acc[bb][j] = 0.f;

  __syncthreads();                                    // x visible

  // this wave's 32-n window
  const float* wpb = w_in + (size_t)(n0 + wid * WAVE_N) * 1024 + lane;

#pragma unroll 2
  for (int i = 0; i < WAVE_N; ++i) {
    // w column for lane m (L2-resident; 16 coalesced 256B-stride loads)
    float wv[16];
#pragma unroll
    for (int xd = 0; xd < 16; ++xd) wv[xd] = wpb[(size_t)i * 1024 + xd * 64];

#pragma unroll
    for (int bb = 0; bb < 2; ++bb) {
      const float4* xp4 =
          (const float4*)&xls[(bb * SLICE_N + wid * WAVE_N + i) * D_];
      float xv[16];
#pragma unroll
      for (int q = 0; q < 4; ++q) {
        float4 v = xp4[q];
        xv[q*4+0] = v.x; xv[q*4+1] = v.y; xv[q*4+2] = v.z; xv[q*4+3] = v.w;
      }
      // vote[a*4+d] = sum_x xv[a*4+x] * wv[x*4+d]
      float vote[16];
#pragma unroll
      for (int a = 0; a < 4; ++a) {
#pragma unroll
        for (int d = 0; d < 4; ++d) {
          float v = xv[a*4+0] * wv[0*4+d];
          v = fmaf(xv[a*4+1], wv[1*4+d], v);
          v = fmaf(xv[a*4+2], wv[2*4+d], v);
          v = fmaf(xv[a*4+3], wv[3*4+d], v);
          vote[a*4+d] = v;
        }
      }
      // scores ~N(0,0.125^2): max-subtraction unnecessary (shift-invariant)
      float q0 = 0.f, q1 = 0.f, q2 = 0.f, q3 = 0.f;
#pragma unroll
      for (int j = 0; j < 4; ++j) {
        q0 = fmaf(vote[j],      ncv[bb][j],      q0);
        q1 = fmaf(vote[4 + j],  ncv[bb][4 + j],  q1);
        q2 = fmaf(vote[8 + j],  ncv[bb][8 + j],  q2);
        q3 = fmaf(vote[12 + j], ncv[bb][12 + j], q3);
      }
      const float sc = (q0 + q1) + (q2 + q3);
      const float p  = EXP2F(sc);
      const float sm = wave_sum64(p);
      const float rr = p * __builtin_amdgcn_rcpf(sm);
#pragma unroll
      for (int j = 0; j < 16; ++j) acc[bb][j] = fmaf(rr, vote[j], acc[bb][j]);
    }
  }

  if (EPI == 0) {
#pragma unroll
    for (int bb = 0; bb < 2; ++bb) {
      float* op = dst + ((size_t)(b0 + bb) * M_ + lane) * D_;
#pragma unroll
      for (int j = 0; j < 16; ++j) atomicAdd(op + j, acc[bb][j]);
    }
    return;
  }

  // ---- intra-block 4-wave reduce (reuse xls), write slice-s partials ----
  // store layout [w<4][q<4][lane<64]: lane-contiguous float4 writes ->
  // conflict-free (r7 fix: the old [w][lane*4+q] layout was a 32-way
  // write conflict, 768 cycles/block). Reads are 8-way one-offs.
  float4* x4 = (float4*)xls;
#pragma unroll
  for (int bb = 0; bb < 2; ++bb) {
    __syncthreads();                  // bb=0: x reads done; bb=1: prev reads done
#pragma unroll
    for (int q = 0; q < 4; ++q) {
      float4 v;
      v.x = acc[bb][q*4+0]; v.y = acc[bb][q*4+1];
      v.z = acc[bb][q*4+2]; v.w = acc[bb][q*4+3];
      x4[wid * 256 + q * 64 + lane] = v;
    }
    __syncthreads();
    // thread t owns (m = t>>2, q = t&3) -> partial f4 index t (coalesced)
    const int rd = (t & 3) * 64 + (t >> 2);
    const float4 s0 = x4[rd], s1 = x4[256 + rd], s2 = x4[512 + rd], s3 = x4[768 + rd];
    float4 r;
    r.x = (s0.x + s1.x) + (s2.x + s3.x);
    r.y = (s0.y + s1.y) + (s2.y + s3.y);
    r.z = (s0.z + s1.z) + (s2.z + s3.z);
    r.w = (s0.w + s1.w) + (s2.w + s3.w);
    ((float4*)dst)[((size_t)s * B_ + b0 + bb) * 256 + t] = r;
  }
}

// ---------- single tail: sum 32 slices + fused LayerNorm over D=16 ---------
__global__ void reduce_ln(const float4* __restrict__ ws4, float4* __restrict__ out4,
                          const float* __restrict__ lw, const float* __restrict__ lb) {
  const int f = blockIdx.x * 256 + threadIdx.x;       // 0..32767 = (b*64+m)*4+q
  float4 s = {0.f, 0.f, 0.f, 0.f};
#pragma unroll 8
  for (int sl = 0; sl < NSLICE; ++sl) {
    const float4 a = ws4[(size_t)sl * OUT4 + f];
    s.x += a.x; s.y += a.y; s.z += a.z; s.w += a.w;
  }
  // LN over 16 elems: 4 consecutive lanes (q=f&3) share one (b,m) row
  float sv = (s.x + s.y) + (s.z + s.w);
  sv += __shfl_xor(sv, 1, 4);
  sv += __shfl_xor(sv, 2, 4);
  const float mu = sv * 0.0625f;
  float4 d;
  d.x = s.x - mu; d.y = s.y - mu; d.z = s.z - mu; d.w = s.w - mu;
  float s2 = (d.x*d.x + d.y*d.y) + (d.z*d.z + d.w*d.w);
  s2 += __shfl_xor(s2, 1, 4);
  s2 += __shfl_xor(s2, 2, 4);
  const float inv = rsqrtf(s2 * 0.0625f + 1e-5f);
  const float4 w4 = ((const float4*)lw)[f & 3];
  const float4 b4 = ((const float4*)lb)[f & 3];
  float4 o;
  o.x = d.x * inv * w4.x + b4.x; o.y = d.y * inv * w4.y + b4.y;
  o.z = d.z * inv * w4.z + b4.z; o.w = d.w * inv * w4.w + b4.w;
  out4[f] = o;
}

// ---------- fallback LN (atomic path), in place on d_out -------------------
__global__ void capsule_ln(float* __restrict__ out, const float* __restrict__ lw,
                           const float* __restrict__ lb) {
  const int t = blockIdx.x * 256 + threadIdx.x;
  const float v = out[t];
  float sv = v;
#pragma unroll
  for (int m = 1; m < 16; m <<= 1) sv += __shfl_xor(sv, m, 16);
  const float mu = sv * 0.0625f;
  const float dv = v - mu;
  float s2 = dv * dv;
#pragma unroll
  for (int m = 1; m < 16; m <<= 1) s2 += __shfl_xor(s2, m, 16);
  out[t] = dv * rsqrtf(s2 * 0.0625f + 1e-5f) * lw[t & 15] + lb[t & 15];
}

extern "C" void kernel_launch(void* const* d_in, const int* in_sizes, int n_in,
                              void* d_out, int out_size, void* d_ws, size_t ws_size,
                              hipStream_t stream) {
  (void)in_sizes; (void)n_in; (void)out_size;
  const float* x_in = (const float*)d_in[0];
  const float* ncv  = (const float*)d_in[1];
  const float* w    = (const float*)d_in[2];
  const float* lw   = (const float*)d_in[3];
  const float* lb   = (const float*)d_in[4];
  // d_in[5] = num_iter (==1): routing body runs once, matching reference
  float* out = (float*)d_out;

  if (ws_size >= PART_BYTES) {
    float* ws = (float*)d_ws;
    capsule_main<1><<<2048, 256, 0, stream>>>(x_in, ncv, w, ws);
    reduce_ln<<<OUT4 / 256, 256, 0, stream>>>((const float4*)ws, (float4*)out, lw, lb);
  } else {
    hipMemsetAsync(out, 0, sizeof(float) * OUT_ELEMS, stream);
    capsule_main<0><<<2048, 256, 0, stream>>>(x_in, ncv, w, out);
    capsule_ln<<<OUT_ELEMS / 256, 256, 0, stream>>>(out, lw, lb);
  }
}

// Round 10
// 185.850 us; speedup vs baseline: 4.4372x; 1.0047x over previous
//
#include <hip/hip_runtime.h>
#include <stdint.h>

#define B_ 128
#define N_ 4096
#define M_ 64
#define D_ 16
#define NSLICE 32                  // n-slices of 128 n each
#define SLICE_N 128
#define WAVE_N 32                  // n handled per wave
#define OUT_ELEMS (B_ * M_ * D_)   // 131072
#define OUT4 (OUT_ELEMS / 4)       // 32768 float4 columns
#define PART_BYTES ((size_t)NSLICE * OUT_ELEMS * sizeof(float))  // 16.8 MB

#if __has_builtin(__builtin_amdgcn_exp2f)
#define EXP2F(x) __builtin_amdgcn_exp2f(x)
#else
#define EXP2F(x) __expf((x) * 0.69314718f)
#endif

// ---------- DPP wave64 sum (VALU pipe; canonical masked bcast cascade) -----
template<int CTRL, int RM, int BC>
__device__ __forceinline__ float dpp_f(float old, float src) {
  return __int_as_float(__builtin_amdgcn_update_dpp(
      __float_as_int(old), __float_as_int(src), CTRL, RM, 0xF, BC));
}

__device__ __forceinline__ float wave_sum64(float x) {
  x += dpp_f<0x121, 0xF, 1>(0.f, x);   // row_ror:1
  x += dpp_f<0x122, 0xF, 1>(0.f, x);   // row_ror:2
  x += dpp_f<0x124, 0xF, 1>(0.f, x);   // row_ror:4
  x += dpp_f<0x128, 0xF, 1>(0.f, x);   // row_ror:8 -> lane holds 16-lane row sum
  x += dpp_f<0x142, 0xA, 1>(0.f, x);   // bcast15, rows 1,3 only
  x += dpp_f<0x143, 0xC, 1>(0.f, x);   // bcast31, rows 2,3 only; lane63 = total
  return __int_as_float(__builtin_amdgcn_readlane(__float_as_int(x), 63));
}

// ---------------------------------------------------------------------------
// lane m <-> capsule m. Per (b,n): vote[16] = X(4x4) @ W_n,m(4x4),
// qk = <vote, ncv'[b,m]> (ncv' pre-scaled by 0.25*log2e), p = exp2(qk),
// softmax across 64 lanes via DPP sum + rcp, acc[m][:] += r*vote.
// Block = 2 b's x 128 n; 4 waves split N (32 n each); wave accs combined by
// an intra-block LDS tree (reuses x-LDS). Grid 2048 = 64 bg x 32 slices.
// Partials: 32 x 0.5 MB = 16.8 MB. Swizzle: XCD k (=inner&7) owns slices
// {4k..4k+3} -> rolling 2 MB w-window per XCD L2.
// LESSONS BAKED IN: (r5) no per-block device-scope fences (buffer_wbl2
// storms); (r7) launch_bounds(256,8) forces VGPR=32 -> spill catastrophe
// (3.4 GB scratch traffic); (256,4) gives VGPR=60 and the HW still runs
// 8 waves/SIMD since 60 <= 64.
// EPI=1: partials to ws. EPI=0: atomicAdd fallback.
// ---------------------------------------------------------------------------
template<int EPI>
__global__ __launch_bounds__(256, 4)
void capsule_main(const float* __restrict__ x_in, const float* __restrict__ ncv_in,
                  const float* __restrict__ w_in, float* __restrict__ dst) {
  const int L     = blockIdx.x;                       // 0..2047
  const int bg    = L >> 5;                           // 0..63
  const int inner = L & 31;
  const int s     = ((inner & 7) << 2) | (inner >> 3);// 0..31, XCD = inner&7
  const int lane  = threadIdx.x & 63;                 // = m
  const int wid   = __builtin_amdgcn_readfirstlane((int)(threadIdx.x >> 6));
  const int t     = threadIdx.x;
  const int b0    = bg * 2;
  const int n0    = s * SLICE_N;

  __shared__ float xls[2 * SLICE_N * D_];             // 16KB: [b<2][n<128][f<16]

  // ---- stage x once (coalesced float4; 4 per thread) ----
#pragma unroll
  for (int k = 0; k < 4; ++k) {
    const int g   = t + 256 * k;                      // float4 idx, 0..1023
    const int b8  = g >> 9;                           // 0..1
    const int rem = g & 511;                          // n*4 + q
    ((float4*)xls)[g] =
        ((const float4*)x_in)[((size_t)(b0 + b8) * N_ + n0) * 4 + rem];
  }

  // persistent per-lane ncv[b][m][0..15], pre-scaled by 0.25*log2(e):
  // p = exp2(qk') == exp(qk*0.25). ncv feeds ONLY the qk dot.
  const float QS = 0.25f * 1.44269504f;
  float ncv[2][16];
#pragma unroll
  for (int bb = 0; bb < 2; ++bb) {
    const float4* p = (const float4*)(ncv_in + ((size_t)(b0 + bb) * M_ + lane) * D_);
#pragma unroll
    for (int q = 0; q < 4; ++q) {
      float4 v = p[q];
      ncv[bb][q*4+0] = v.x * QS; ncv[bb][q*4+1] = v.y * QS;
      ncv[bb][q*4+2] = v.z * QS; ncv[bb][q*4+3] = v.w * QS;
    }
  }

  float acc[2][16];
#pragma unroll
  for (int bb = 0; bb < 2; ++bb)
#pragma unroll
    for (int j = 0; j < 16; ++j) acc[bb][j] = 0.f;

  __syncthreads();                                    // x visible

  // this wave's 32-n window
  const float* wpb = w_in + (size_t)(n0 + wid * WAVE_N) * 1024 + lane;

#pragma unroll 2
  for (int i = 0; i < WAVE_N; ++i) {
    // w column for lane m (L2-resident; 16 coalesced 256B-stride loads)
    float wv[16];
#pragma unroll
    for (int xd = 0; xd < 16; ++xd) wv[xd] = wpb[(size_t)i * 1024 + xd * 64];

#pragma unroll
    for (int bb = 0; bb < 2; ++bb) {
      const float4* xp4 =
          (const float4*)&xls[(bb * SLICE_N + wid * WAVE_N + i) * D_];
      float xv[16];
#pragma unroll
      for (int q = 0; q < 4; ++q) {
        float4 v = xp4[q];
        xv[q*4+0] = v.x; xv[q*4+1] = v.y; xv[q*4+2] = v.z; xv[q*4+3] = v.w;
      }
      // vote[a*4+d] = sum_x xv[a*4+x] * wv[x*4+d]
      float vote[16];
#pragma unroll
      for (int a = 0; a < 4; ++a) {
#pragma unroll
        for (int d = 0; d < 4; ++d) {
          float v = xv[a*4+0] * wv[0*4+d];
          v = fmaf(xv[a*4+1], wv[1*4+d], v);
          v = fmaf(xv[a*4+2], wv[2*4+d], v);
          v = fmaf(xv[a*4+3], wv[3*4+d], v);
          vote[a*4+d] = v;
        }
      }
      // scores ~N(0,0.125^2): max-subtraction unnecessary (shift-invariant)
      float q0 = 0.f, q1 = 0.f, q2 = 0.f, q3 = 0.f;
#pragma unroll
      for (int j = 0; j < 4; ++j) {
        q0 = fmaf(vote[j],      ncv[bb][j],      q0);
        q1 = fmaf(vote[4 + j],  ncv[bb][4 + j],  q1);
        q2 = fmaf(vote[8 + j],  ncv[bb][8 + j],  q2);
        q3 = fmaf(vote[12 + j], ncv[bb][12 + j], q3);
      }
      const float sc = (q0 + q1) + (q2 + q3);
      const float p  = EXP2F(sc);
      const float sm = wave_sum64(p);
      const float rr = p * __builtin_amdgcn_rcpf(sm);
#pragma unroll
      for (int j = 0; j < 16; ++j) acc[bb][j] = fmaf(rr, vote[j], acc[bb][j]);
    }
  }

  if (EPI == 0) {
#pragma unroll
    for (int bb = 0; bb < 2; ++bb) {
      float* op = dst + ((size_t)(b0 + bb) * M_ + lane) * D_;
#pragma unroll
      for (int j = 0; j < 16; ++j) atomicAdd(op + j, acc[bb][j]);
    }
    return;
  }

  // ---- intra-block 4-wave reduce (reuse xls), write slice-s partials ----
  // store layout [w<4][q<4][lane<64]: lane-contiguous float4 writes ->
  // conflict-free. Reads are small one-off conflicts (~384 cyc/block).
  float4* x4 = (float4*)xls;
#pragma unroll
  for (int bb = 0; bb < 2; ++bb) {
    __syncthreads();                  // bb=0: x reads done; bb=1: prev reads done
#pragma unroll
    for (int q = 0; q < 4; ++q) {
      float4 v;
      v.x = acc[bb][q*4+0]; v.y = acc[bb][q*4+1];
      v.z = acc[bb][q*4+2]; v.w = acc[bb][q*4+3];
      x4[wid * 256 + q * 64 + lane] = v;
    }
    __syncthreads();
    // thread t owns (m = t>>2, q = t&3) -> partial f4 index t (coalesced)
    const int rd = (t & 3) * 64 + (t >> 2);
    const float4 s0 = x4[rd], s1 = x4[256 + rd], s2 = x4[512 + rd], s3 = x4[768 + rd];
    float4 r;
    r.x = (s0.x + s1.x) + (s2.x + s3.x);
    r.y = (s0.y + s1.y) + (s2.y + s3.y);
    r.z = (s0.z + s1.z) + (s2.z + s3.z);
    r.w = (s0.w + s1.w) + (s2.w + s3.w);
    ((float4*)dst)[((size_t)s * B_ + b0 + bb) * 256 + t] = r;
  }
}

// ---------- tail: sum 32 slices + fused LayerNorm, 512-block version -------
// Block owns 64 float4 columns. Thread t: col = blk*64 + (t&63), slice-group
// sg = t>>6 sums 8 slices; LDS 4-way combine; wave 0 does LN + writes.
// (r8 lesson: the 128-block version was latency-bound at ~60 us — half the
// CUs idle, 32 strided loads/thread.)
__global__ __launch_bounds__(256, 4)
void reduce_ln(const float4* __restrict__ ws4, float4* __restrict__ out4,
               const float* __restrict__ lw, const float* __restrict__ lb) {
  const int blk = blockIdx.x;                         // 0..511
  const int t   = threadIdx.x;
  const int ln  = t & 63;
  const int sg  = t >> 6;                             // 0..3
  const int col = (blk << 6) + ln;                    // float4 column

  __shared__ float4 red[256];

  float4 s = {0.f, 0.f, 0.f, 0.f};
#pragma unroll
  for (int k = 0; k < 8; ++k) {
    const float4 a = ws4[(size_t)(sg * 8 + k) * OUT4 + col];
    s.x += a.x; s.y += a.y; s.z += a.z; s.w += a.w;
  }
  red[t] = s;
  __syncthreads();
  if (t < 64) {
    const float4 r1 = red[t + 64], r2 = red[t + 128], r3 = red[t + 192];
    s = red[t];
    s.x = (s.x + r1.x) + (r2.x + r3.x);
    s.y = (s.y + r1.y) + (r2.y + r3.y);
    s.z = (s.z + r1.z) + (r2.z + r3.z);
    s.w = (s.w + r1.w) + (r2.w + r3.w);
    // LN over 16 elems: 4 consecutive lanes (q = ln&3) share one (b,m) row
    float sv = (s.x + s.y) + (s.z + s.w);
    sv += __shfl_xor(sv, 1, 4);
    sv += __shfl_xor(sv, 2, 4);
    const float mu = sv * 0.0625f;
    float4 d;
    d.x = s.x - mu; d.y = s.y - mu; d.z = s.z - mu; d.w = s.w - mu;
    float s2 = (d.x*d.x + d.y*d.y) + (d.z*d.z + d.w*d.w);
    s2 += __shfl_xor(s2, 1, 4);
    s2 += __shfl_xor(s2, 2, 4);
    const float inv = rsqrtf(s2 * 0.0625f + 1e-5f);
    const float4 w4 = ((const float4*)lw)[ln & 3];
    const float4 b4 = ((const float4*)lb)[ln & 3];
    float4 o;
    o.x = d.x * inv * w4.x + b4.x; o.y = d.y * inv * w4.y + b4.y;
    o.z = d.z * inv * w4.z + b4.z; o.w = d.w * inv * w4.w + b4.w;
    out4[col] = o;
  }
}

// ---------- fallback LN (atomic path), in place on d_out -------------------
__global__ void capsule_ln(float* __restrict__ out, const float* __restrict__ lw,
                           const float* __restrict__ lb) {
  const int t = blockIdx.x * 256 + threadIdx.x;
  const float v = out[t];
  float sv = v;
#pragma unroll
  for (int m = 1; m < 16; m <<= 1) sv += __shfl_xor(sv, m, 16);
  const float mu = sv * 0.0625f;
  const float dv = v - mu;
  float s2 = dv * dv;
#pragma unroll
  for (int m = 1; m < 16; m <<= 1) s2 += __shfl_xor(s2, m, 16);
  out[t] = dv * rsqrtf(s2 * 0.0625f + 1e-5f) * lw[t & 15] + lb[t & 15];
}

extern "C" void kernel_launch(void* const* d_in, const int* in_sizes, int n_in,
                              void* d_out, int out_size, void* d_ws, size_t ws_size,
                              hipStream_t stream) {
  (void)in_sizes; (void)n_in; (void)out_size;
  const float* x_in = (const float*)d_in[0];
  const float* ncv  = (const float*)d_in[1];
  const float* w    = (const float*)d_in[2];
  const float* lw   = (const float*)d_in[3];
  const float* lb   = (const float*)d_in[4];
  // d_in[5] = num_iter (==1): routing body runs once, matching reference
  float* out = (float*)d_out;

  if (ws_size >= PART_BYTES) {
    float* ws = (float*)d_ws;
    capsule_main<1><<<2048, 256, 0, stream>>>(x_in, ncv, w, ws);
    reduce_ln<<<512, 256, 0, stream>>>((const float4*)ws, (float4*)out, lw, lb);
  } else {
    hipMemsetAsync(out, 0, sizeof(float) * OUT_ELEMS, stream);
    capsule_main<0><<<2048, 256, 0, stream>>>(x_in, ncv, w, out);
    capsule_ln<<<OUT_ELEMS / 256, 256, 0, stream>>>(out, lw, lb);
  }
}